// Round 1
// baseline (106.535 us; speedup 1.0000x reference)
//
#include <hip/hip_runtime.h>

// BootstrapLoss: mean of the top-20% per-pixel (channel-mean) squared errors.
// input/target: [64, 3, 256, 256] fp32. N_pix = 64*256*256 = 4194304.
// k = N - int(0.8*N) = 838861 largest values; output = their mean (scalar f32).
//
// Strategy: two-level histogram selection on the float bit pattern
// (non-negative floats sort like uint32 bit patterns).
//   pass1 : compute mse per pixel -> ws (16MB), hist1 over bits[31:19] (4096 bins)
//   sel1  : find bin b1 containing the k-th largest, residual r1
//   pass2 : sum values in bins > b1 (double); hist2+sum2 over bits[18:7] for bin b1
//   sel2  : find sub-bin b2, residual r2; result = (sum_hi + sum_above + r2*avg)/k
// Final-bucket values agree in their top 25 bits -> tie approximation error
// < 0.3 absolute vs result ~2.2e4 (tolerance 448).

#define NPIX   (64 * 256 * 256)   // 4194304
#define NV4    (NPIX / 4)         // 1048576
#define HW     65536
#define CHW    196608
#define KTAIL  838861             // 4194304 - int(0.8 * 4194304)
#define NBIN   4096

__device__ inline float sqf(float x) { return x * x; }

// mse for 4 consecutive pixels (vec4 index i); HW is a multiple of 4 so a
// group of 4 pixels never crosses a batch/channel row -> aligned float4 loads.
__device__ inline float4 mse4(const float4* __restrict__ in,
                              const float4* __restrict__ tg, int i) {
  int p  = i << 2;
  int b  = p >> 16;          // p / HW
  int hw = p & (HW - 1);
  int base4 = (b * CHW + hw) >> 2;
  float4 a0 = in[base4];
  float4 a1 = in[base4 + HW / 4];
  float4 a2 = in[base4 + HW / 2];
  float4 t0 = tg[base4];
  float4 t1 = tg[base4 + HW / 4];
  float4 t2 = tg[base4 + HW / 2];
  const float S = 65025.0f / 3.0f;   // (255^2)/3
  float4 v;
  v.x = (sqf(a0.x - t0.x) + sqf(a1.x - t1.x) + sqf(a2.x - t2.x)) * S;
  v.y = (sqf(a0.y - t0.y) + sqf(a1.y - t1.y) + sqf(a2.y - t2.y)) * S;
  v.z = (sqf(a0.z - t0.z) + sqf(a1.z - t1.z) + sqf(a2.z - t2.z)) * S;
  v.w = (sqf(a0.w - t0.w) + sqf(a1.w - t1.w) + sqf(a2.w - t2.w)) * S;
  return v;
}

template <bool STORE>
__global__ __launch_bounds__(256)
void k_pass1(const float4* __restrict__ in, const float4* __restrict__ tg,
             float4* __restrict__ vals, unsigned* __restrict__ hist1) {
  __shared__ unsigned h[NBIN];
  for (int i = threadIdx.x; i < NBIN; i += 256) h[i] = 0u;
  __syncthreads();
  const int stride = gridDim.x * blockDim.x;
  for (int i = blockIdx.x * blockDim.x + threadIdx.x; i < NV4; i += stride) {
    float4 v = mse4(in, tg, i);
    atomicAdd(&h[__float_as_uint(v.x) >> 19], 1u);
    atomicAdd(&h[__float_as_uint(v.y) >> 19], 1u);
    atomicAdd(&h[__float_as_uint(v.z) >> 19], 1u);
    atomicAdd(&h[__float_as_uint(v.w) >> 19], 1u);
    if (STORE) vals[i] = v;
  }
  __syncthreads();
  for (int i = threadIdx.x; i < NBIN; i += 256)
    if (h[i]) atomicAdd(&hist1[i], h[i]);
}

// sel[0] = b1 (bin containing the k-th largest), sel[1] = r1 (count needed
// from bin b1).
__global__ void k_sel1(const unsigned* __restrict__ hist1, int* __restrict__ sel) {
  __shared__ unsigned h[NBIN];
  __shared__ unsigned csum[256];
  const int t = threadIdx.x;
  unsigned local = 0u;
  for (int j = 0; j < 16; ++j) {
    unsigned c = hist1[t * 16 + j];
    h[t * 16 + j] = c;
    local += c;
  }
  csum[t] = local;
  __syncthreads();
  if (t == 0) {
    long cum = 0;
    int chunk = 255;
    for (; chunk > 0; --chunk) {
      if (cum + (long)csum[chunk] >= (long)KTAIL) break;
      cum += csum[chunk];
    }
    int b = chunk * 16 + 15;
    for (; b > 0; --b) {
      unsigned c = h[b];
      if (cum + (long)c >= (long)KTAIL) break;
      cum += c;
    }
    sel[0] = b;
    sel[1] = (int)((long)KTAIL - cum);
  }
}

template <bool STORE>
__global__ __launch_bounds__(256)
void k_pass2(const float4* __restrict__ vals,
             const float4* __restrict__ in, const float4* __restrict__ tg,
             const int* __restrict__ sel,
             unsigned* __restrict__ hist2, double* __restrict__ sum2,
             double* __restrict__ sum_hi) {
  __shared__ unsigned h[NBIN];
  __shared__ float fs[NBIN];
  __shared__ double red[256];
  for (int i = threadIdx.x; i < NBIN; i += 256) { h[i] = 0u; fs[i] = 0.0f; }
  __syncthreads();
  const unsigned b1 = (unsigned)sel[0];
  double local = 0.0;
  const int stride = gridDim.x * blockDim.x;
  for (int i = blockIdx.x * blockDim.x + threadIdx.x; i < NV4; i += stride) {
    float4 v = STORE ? vals[i] : mse4(in, tg, i);
    float vv[4] = {v.x, v.y, v.z, v.w};
#pragma unroll
    for (int c = 0; c < 4; ++c) {
      unsigned bits = __float_as_uint(vv[c]);
      unsigned bb = bits >> 19;
      if (bb > b1) {
        local += (double)vv[c];
      } else if (bb == b1) {
        unsigned s = (bits >> 7) & (NBIN - 1);
        atomicAdd(&h[s], 1u);
        atomicAdd(&fs[s], vv[c]);
      }
    }
  }
  __syncthreads();
  for (int i = threadIdx.x; i < NBIN; i += 256)
    if (h[i]) {
      atomicAdd(&hist2[i], h[i]);
      atomicAdd(&sum2[i], (double)fs[i]);
    }
  red[threadIdx.x] = local;
  __syncthreads();
  for (int off = 128; off > 0; off >>= 1) {
    if (threadIdx.x < off) red[threadIdx.x] += red[threadIdx.x + off];
    __syncthreads();
  }
  if (threadIdx.x == 0 && red[0] != 0.0) atomicAdd(sum_hi, red[0]);
}

__global__ void k_sel2(const unsigned* __restrict__ hist2,
                       const double* __restrict__ sum2,
                       const double* __restrict__ sum_hi,
                       const int* __restrict__ sel,
                       float* __restrict__ out) {
  __shared__ unsigned h[NBIN];
  __shared__ double fsum[NBIN];
  __shared__ unsigned csum[256];
  __shared__ double dsum[256];
  const int t = threadIdx.x;
  unsigned localc = 0u;
  double locald = 0.0;
  for (int j = 0; j < 16; ++j) {
    int idx = t * 16 + j;
    unsigned c = hist2[idx];
    double d = sum2[idx];
    h[idx] = c;
    fsum[idx] = d;
    localc += c;
    locald += d;
  }
  csum[t] = localc;
  dsum[t] = locald;
  __syncthreads();
  if (t == 0) {
    const long r1 = (long)sel[1];
    long cum = 0;
    double above = 0.0;
    int chunk = 255;
    for (; chunk > 0; --chunk) {
      if (cum + (long)csum[chunk] >= r1) break;
      cum += csum[chunk];
      above += dsum[chunk];
    }
    int s = chunk * 16 + 15;
    for (; s > 0; --s) {
      unsigned c = h[s];
      if (cum + (long)c >= r1) break;
      cum += c;
      above += fsum[s];
    }
    long r2 = r1 - cum;
    unsigned cs = h[s];
    double tie = (cs > 0u) ? (fsum[s] / (double)cs) : 0.0;
    double total = *sum_hi + above + (double)r2 * tie;
    out[0] = (float)(total / (double)KTAIL);
  }
}

extern "C" void kernel_launch(void* const* d_in, const int* in_sizes, int n_in,
                              void* d_out, int out_size, void* d_ws, size_t ws_size,
                              hipStream_t stream) {
  (void)in_sizes; (void)n_in; (void)out_size;
  const float4* in = (const float4*)d_in[0];
  const float4* tg = (const float4*)d_in[1];
  float* out = (float*)d_out;
  char* ws = (char*)d_ws;

  const size_t VALS_BYTES = (size_t)NPIX * 4;                        // 16 MB
  const size_t ACC_BYTES  = NBIN * 4 + NBIN * 4 + NBIN * 8 + 16;     // 65552
  const bool store = ws_size >= VALS_BYTES + ACC_BYTES;
  const size_t off = store ? VALS_BYTES : 0;

  unsigned* hist1  = (unsigned*)(ws + off);
  unsigned* hist2  = hist1 + NBIN;
  double*   sum2   = (double*)(hist2 + NBIN);
  double*   sum_hi = sum2 + NBIN;
  int*      sel    = (int*)(sum_hi + 1);
  float4*   vals   = (float4*)ws;

  // zero all accumulators every call (harness does not re-poison between replays)
  hipMemsetAsync(hist1, 0, ACC_BYTES, stream);

  dim3 blk(256), grd(2048);
  if (store)
    k_pass1<true><<<grd, blk, 0, stream>>>(in, tg, vals, hist1);
  else
    k_pass1<false><<<grd, blk, 0, stream>>>(in, tg, nullptr, hist1);

  k_sel1<<<1, 256, 0, stream>>>(hist1, sel);

  if (store)
    k_pass2<true><<<grd, blk, 0, stream>>>(vals, in, tg, sel, hist2, sum2, sum_hi);
  else
    k_pass2<false><<<grd, blk, 0, stream>>>(nullptr, in, tg, sel, hist2, sum2, sum_hi);

  k_sel2<<<1, 256, 0, stream>>>(hist2, sum2, sum_hi, sel, out);
}

// Round 2
// 59.682 us; speedup vs baseline: 1.7851x; 1.7851x over previous
//
#include <hip/hip_runtime.h>

// BootstrapLoss: mean of the top-20% per-pixel (channel-mean) squared errors.
// input/target: [64, 3, 256, 256] fp32. N_pix = 64*256*256 = 4194304.
// k = N - int(0.8*N) = 838861 largest; output = their mean (scalar f32).
//
// Single-pass histogram selection on the float bit pattern (non-negative
// floats order like their uint32 bit patterns). 4096 bins = sign+exp+4
// mantissa bits (bits>>19). Per bin we keep COUNT and SUM; the k-th-largest
// bin's partial contribution uses the bin average. Worst-case tie error
// ~ c_bin * width / (8k) ~ 25 absolute vs tolerance 448.

#define NPIX   (64 * 256 * 256)   // 4194304
#define NV4    (NPIX / 4)         // 1048576
#define HW     65536
#define CHW    196608
#define KTAIL  838861             // 4194304 - int(0.8 * 4194304)
#define NBIN   4096

__device__ inline float sqf(float x) { return x * x; }

// mse for 4 consecutive pixels (vec4 index i); HW is a multiple of 4 so a
// group of 4 pixels never crosses a batch/channel row -> aligned float4 loads.
__device__ inline float4 mse4(const float4* __restrict__ in,
                              const float4* __restrict__ tg, int i) {
  int p  = i << 2;
  int b  = p >> 16;          // p / HW
  int hw = p & (HW - 1);
  int base4 = (b * CHW + hw) >> 2;
  float4 a0 = in[base4];
  float4 a1 = in[base4 + HW / 4];
  float4 a2 = in[base4 + HW / 2];
  float4 t0 = tg[base4];
  float4 t1 = tg[base4 + HW / 4];
  float4 t2 = tg[base4 + HW / 2];
  const float S = 65025.0f / 3.0f;   // (255^2)/3
  float4 v;
  v.x = (sqf(a0.x - t0.x) + sqf(a1.x - t1.x) + sqf(a2.x - t2.x)) * S;
  v.y = (sqf(a0.y - t0.y) + sqf(a1.y - t1.y) + sqf(a2.y - t2.y)) * S;
  v.z = (sqf(a0.z - t0.z) + sqf(a1.z - t1.z) + sqf(a2.z - t2.z)) * S;
  v.w = (sqf(a0.w - t0.w) + sqf(a1.w - t1.w) + sqf(a2.w - t2.w)) * S;
  return v;
}

// 1024 blocks x 256 threads x 4 unrolled vec4 iters = NV4 exactly.
__global__ __launch_bounds__(256)
void k_main(const float4* __restrict__ in, const float4* __restrict__ tg,
            unsigned* __restrict__ gcnt, double* __restrict__ gsum) {
  __shared__ unsigned h[NBIN];
  __shared__ float fs[NBIN];
  for (int i = threadIdx.x; i < NBIN; i += 256) { h[i] = 0u; fs[i] = 0.0f; }
  __syncthreads();

  const int base = blockIdx.x * 1024 + threadIdx.x;
  float4 vr[4];
#pragma unroll
  for (int u = 0; u < 4; ++u)
    vr[u] = mse4(in, tg, base + u * 256);   // 24 independent float4 loads

#pragma unroll
  for (int u = 0; u < 4; ++u) {
    float vv[4] = {vr[u].x, vr[u].y, vr[u].z, vr[u].w};
#pragma unroll
    for (int c = 0; c < 4; ++c) {
      unsigned b = __float_as_uint(vv[c]) >> 19;
      atomicAdd(&h[b], 1u);
      atomicAdd(&fs[b], vv[c]);
    }
  }
  __syncthreads();

  for (int i = threadIdx.x; i < NBIN; i += 256) {
    unsigned c = h[i];
    if (c) {
      atomicAdd(&gcnt[i], c);
      atomicAdd(&gsum[i], (double)fs[i]);
    }
  }
}

__global__ void k_final(const unsigned* __restrict__ gcnt,
                        const double* __restrict__ gsum,
                        float* __restrict__ out) {
  __shared__ unsigned h[NBIN];
  __shared__ double s[NBIN];
  __shared__ unsigned cc[256];
  __shared__ double cs[256];
  const int t = threadIdx.x;
  unsigned lc = 0u;
  double ls = 0.0;
  for (int j = 0; j < 16; ++j) {
    int idx = t * 16 + j;
    unsigned c = gcnt[idx];
    double d = gsum[idx];
    h[idx] = c;
    s[idx] = d;
    lc += c;
    ls += d;
  }
  cc[t] = lc;
  cs[t] = ls;
  __syncthreads();
  if (t == 0) {
    long cum = 0;
    double above = 0.0;
    int chunk = 255;
    for (; chunk > 0; --chunk) {
      if (cum + (long)cc[chunk] >= (long)KTAIL) break;
      cum += cc[chunk];
      above += cs[chunk];
    }
    int b = chunk * 16 + 15;
    for (; b > 0; --b) {
      unsigned c = h[b];
      if (cum + (long)c >= (long)KTAIL) break;
      cum += c;
      above += s[b];
    }
    long r = (long)KTAIL - cum;
    unsigned cb = h[b];
    double avg = cb ? s[b] / (double)cb : 0.0;
    out[0] = (float)((above + (double)r * avg) / (double)KTAIL);
  }
}

extern "C" void kernel_launch(void* const* d_in, const int* in_sizes, int n_in,
                              void* d_out, int out_size, void* d_ws, size_t ws_size,
                              hipStream_t stream) {
  (void)in_sizes; (void)n_in; (void)out_size; (void)ws_size;
  const float4* in = (const float4*)d_in[0];
  const float4* tg = (const float4*)d_in[1];
  float* out = (float*)d_out;
  char* ws = (char*)d_ws;

  unsigned* gcnt = (unsigned*)ws;                  // 16 KB
  double*   gsum = (double*)(ws + NBIN * 4);       // 32 KB (8-aligned)

  // zero accumulators every call (harness does not re-poison between replays)
  hipMemsetAsync(gcnt, 0, NBIN * 4 + NBIN * 8, stream);

  k_main<<<dim3(1024), dim3(256), 0, stream>>>(in, tg, gcnt, gsum);
  k_final<<<1, 256, 0, stream>>>(gcnt, gsum, out);
}